// Round 2
// 533.252 us; speedup vs baseline: 1.0063x; 1.0063x over previous
//
#include <hip/hip_runtime.h>

// JPEG decode, fully fused: dequant + separable 8x8 IDCT + unblock +
// 2x chroma upsample + YCbCr->RGB + clip/255, one kernel, no workspace.
//
// Fixed problem size from setup_inputs(): B=8, H=2048, W=2048.
// Tile: 16 rows x 128 cols of output per 256-thread workgroup.
//   -> 32 Y blocks (2x16), 8 Cb blocks, 8 Cr blocks per tile.
//
// R1 changes vs baseline (theory: LDS-pipe bound, not HBM bound):
//  - pass-2 IDCT basis hardcoded as literals (was 64 ds_read_b32/thread/IDCT)
//  - cv[] hoisted once per thread, shared by Y and chroma IDCT (same v=tid&7)
//  - Y + chroma coeffs staged together; 3 __syncthreads instead of 5;
//    all global coeff loads issued before the first sync
//  - coef stride 72 -> 68 (bank step 4: 8 b128 reads/wave cover 32 banks once)
//  - float4 quant-table reads, float2 chroma pixel reads, nontemporal stores
// R2: nontemporal stores use clang ext_vector_type (HIP float4 class is
//     rejected by __builtin_nontemporal_store).

#define H 2048
#define W 2048
#define YBLK_COLS (W / 8)     // 256
#define CBLK_COLS (W / 16)    // 128
#define CSTRIDE 68            // floats per staged 8x8 block (16B-aligned, bank step 4)

typedef float f32x4 __attribute__((ext_vector_type(4)));

// CT[x][u] = cos((2u+1)*x*pi/16), float32-rounded.
// Bit-identical to dct_tensor[x,0,u,0] (c[0][0]==1.0f exactly).
constexpr float CT[8][8] = {
    {  1.0f,                   1.0f,                   1.0f,                   1.0f,
       1.0f,                   1.0f,                   1.0f,                   1.0f },
    {  0.980785280403230449f,  0.831469612302545237f,  0.555570233019602225f,  0.195090322016128268f,
      -0.195090322016128268f, -0.555570233019602225f, -0.831469612302545237f, -0.980785280403230449f },
    {  0.923879532511286756f,  0.382683432365089772f, -0.382683432365089772f, -0.923879532511286756f,
      -0.923879532511286756f, -0.382683432365089772f,  0.382683432365089772f,  0.923879532511286756f },
    {  0.831469612302545237f, -0.195090322016128268f, -0.980785280403230449f, -0.555570233019602225f,
       0.555570233019602225f,  0.980785280403230449f,  0.195090322016128268f, -0.831469612302545237f },
    {  0.707106781186547524f, -0.707106781186547524f, -0.707106781186547524f,  0.707106781186547524f,
       0.707106781186547524f, -0.707106781186547524f, -0.707106781186547524f,  0.707106781186547524f },
    {  0.555570233019602225f, -0.980785280403230449f,  0.195090322016128268f,  0.831469612302545237f,
      -0.831469612302545237f, -0.195090322016128268f,  0.980785280403230449f, -0.555570233019602225f },
    {  0.382683432365089772f, -0.923879532511286756f,  0.923879532511286756f, -0.382683432365089772f,
      -0.382683432365089772f,  0.923879532511286756f, -0.923879532511286756f,  0.382683432365089772f },
    {  0.195090322016128268f, -0.555570233019602225f,  0.831469612302545237f, -0.980785280403230449f,
       0.980785280403230449f, -0.831469612302545237f,  0.555570233019602225f, -0.195090322016128268f },
};

__global__ __launch_bounds__(256) void jpeg_decode_kernel(
    const float* __restrict__ yg,
    const float* __restrict__ cbg,
    const float* __restrict__ crg,
    const float* __restrict__ y_table,
    const float* __restrict__ c_table,
    const float* __restrict__ alpha,
    const float* __restrict__ dct,
    const float* __restrict__ shiftp,
    const float* __restrict__ matp,
    const int* __restrict__ factor_p,
    float* __restrict__ out)
{
    __shared__ float qY[64];              // y_table*factor*alpha
    __shared__ float qC[64];              // c_table*factor*alpha
    __shared__ float cosT[64];            // cos((2u+1)x pi/16), for runtime-v pass-1 reads
    __shared__ float matS[9];
    __shared__ float shiftS[3];
    __shared__ float coef[48 * CSTRIDE];  // 32 Y + 8 Cb + 8 Cr dequantized blocks
    __shared__ float pixY[16 * 128];
    __shared__ float pixCb[8 * 64];
    __shared__ float pixCr[8 * 64];

    const int tid = threadIdx.x;
    const int b  = blockIdx.z;   // batch
    const int th = blockIdx.y;   // tile row  0..127
    const int tw = blockIdx.x;   // tile col  0..15

    // ---- setup: tables (threads 0..75) ----
    if (tid < 64) {
        const float f = (float)factor_p[0];
        qY[tid] = y_table[tid] * f * alpha[tid];
        qC[tid] = c_table[tid] * f * alpha[tid];
        const int x = tid >> 3, u = tid & 7;
        cosT[tid] = dct[x * 512 + u * 8];   // = CT[x][u], bit-identical
    } else if (tid < 73) {
        matS[tid - 64] = matp[tid - 64];
    } else if (tid < 76) {
        shiftS[tid - 73] = shiftp[tid - 73];
    }

    // ---- issue ALL coefficient global loads before the table sync ----
    const int flatY = tid * 4;           // 0..1020
    const size_t baseY =
        (((size_t)b * (YBLK_COLS * (H / 8))) + (size_t)(2 * th) * YBLK_COLS + (size_t)tw * 16) * 64;
    const float4 y0 = *(const float4*)(yg + baseY + flatY);
    const float4 y1 = *(const float4*)(yg + baseY + 16384 + flatY);

    const int half  = tid >> 7;          // 0 = Cb, 1 = Cr
    const int flatC = (tid & 127) * 4;   // 0..508
    const float* srcC = half ? crg : cbg;
    const size_t baseC =
        (((size_t)b * (CBLK_COLS * (H / 16))) + (size_t)th * CBLK_COLS + (size_t)tw * 8) * 64;
    const float4 c0 = *(const float4*)(srcC + baseC + flatC);

    __syncthreads();   // tables ready

    // ---- dequant + stage Y (32 blocks) and chroma (16 blocks) into LDS ----
    {
        const int within = flatY & 63;
        const float4 qv = *(const float4*)&qY[within];
        const int blk0 = flatY >> 6;     // 0..15
        float4 w0, w1;
        w0.x = y0.x * qv.x; w0.y = y0.y * qv.y; w0.z = y0.z * qv.z; w0.w = y0.w * qv.w;
        w1.x = y1.x * qv.x; w1.y = y1.y * qv.y; w1.z = y1.z * qv.z; w1.w = y1.w * qv.w;
        *(float4*)&coef[blk0 * CSTRIDE + within]        = w0;
        *(float4*)&coef[(16 + blk0) * CSTRIDE + within] = w1;

        const int withinC = flatC & 63;
        const float4 qc = *(const float4*)&qC[withinC];
        const int blkC = 32 + half * 8 + (flatC >> 6);
        float4 wc;
        wc.x = c0.x * qc.x; wc.y = c0.y * qc.y; wc.z = c0.z * qc.z; wc.w = c0.w * qc.w;
        *(float4*)&coef[blkC * CSTRIDE + withinC] = wc;
    }
    __syncthreads();   // coef ready

    // ---- separable IDCT: thread owns one (block, v) column ----
    // out[u,v] = 0.25 * sum_x CT[x][u] * (sum_y D[x,y] * CT[y][v]) + 128
    // pass-1 constants (runtime v) from LDS; pass-2 constants are literals.
    const int v = tid & 7;
    float cv[8];
#pragma unroll
    for (int yy = 0; yy < 8; yy++) cv[yy] = cosT[yy * 8 + v];

    auto idct8 = [&](const float* Dp, float* p) {
        float t[8];
#pragma unroll
        for (int x = 0; x < 8; x++) {
            const float4 a = *(const float4*)(Dp + x * 8);
            const float4 c = *(const float4*)(Dp + x * 8 + 4);
            t[x] = a.x * cv[0] + a.y * cv[1] + a.z * cv[2] + a.w * cv[3]
                 + c.x * cv[4] + c.y * cv[5] + c.z * cv[6] + c.w * cv[7];
        }
#pragma unroll
        for (int u = 0; u < 8; u++) {
            float s = 0.f;
#pragma unroll
            for (int x = 0; x < 8; x++) s += t[x] * CT[x][u];
            p[u] = 0.25f * s + 128.0f;
        }
    };

    // Y IDCT: 256 threads = 32 blocks x 8 v-columns
    {
        const int bh  = tid >> 7;       // 0..1
        const int rem = tid & 127;      // col within tile
        const int bw  = rem >> 3;       // 0..15
        const float* Dp = &coef[(bh * 16 + bw) * CSTRIDE];
        float p[8];
        idct8(Dp, p);
#pragma unroll
        for (int u = 0; u < 8; u++) pixY[(bh * 8 + u) * 128 + rem] = p[u];
    }
    // chroma IDCT: 128 threads = 16 blocks x 8 v-columns (same v per thread)
    if (tid < 128) {
        const int blk = tid >> 3;       // 0..15 (0-7 Cb, 8-15 Cr)
        const float* Dp = &coef[(32 + blk) * CSTRIDE];
        float p[8];
        idct8(Dp, p);
        float* dst = (blk >= 8) ? pixCr : pixCb;
        const int col = (blk & 7) * 8 + v;
#pragma unroll
        for (int u = 0; u < 8; u++) dst[u * 64 + col] = p[u];
    }
    __syncthreads();   // pixY / pixCb / pixCr ready

    // ---- fused upsample + color convert + clip + store ----
    {
        const float s0 = shiftS[0], s1 = shiftS[1], s2 = shiftS[2];
        const float m0 = matS[0], m1 = matS[1], m2 = matS[2];
        const float m3 = matS[3], m4 = matS[4], m5 = matS[5];
        const float m6 = matS[6], m7 = matS[7], m8 = matS[8];
        const float inv255 = 1.0f / 255.0f;
        const size_t planeStride = (size_t)H * W;
        const size_t outBase = (size_t)b * 3 * planeStride;

#pragma unroll
        for (int it = 0; it < 2; it++) {
            const int idx = it * 256 + tid;     // 0..511
            const int r  = idx >> 5;            // 0..15
            const int c4 = (idx & 31) << 2;     // 0..124, step 4
            const float4 yv = *(const float4*)&pixY[r * 128 + c4];
            const int rc = r >> 1, cc = c4 >> 1;        // cc even -> 8B aligned
            const float2 cbv2 = *(const float2*)&pixCb[rc * 64 + cc];
            const float2 crv2 = *(const float2*)&pixCr[rc * 64 + cc];
            const float yy[4] = { yv.x + s0, yv.y + s0, yv.z + s0, yv.w + s0 };
            const float cbv[2] = { cbv2.x + s1, cbv2.y + s1 };
            const float crv[2] = { crv2.x + s2, crv2.y + s2 };

            f32x4 R, G, Bv;
#pragma unroll
            for (int j = 0; j < 4; j++) {
                const int h2 = j >> 1;
                const float Yv = yy[j], Cb = cbv[h2], Cr = crv[h2];
                const float r_ = Yv * m0 + Cb * m3 + Cr * m6;
                const float g_ = Yv * m1 + Cb * m4 + Cr * m7;
                const float b_ = Yv * m2 + Cb * m5 + Cr * m8;
                R[j]  = fminf(fmaxf(r_, 0.0f), 255.0f) * inv255;
                G[j]  = fminf(fmaxf(g_, 0.0f), 255.0f) * inv255;
                Bv[j] = fminf(fmaxf(b_, 0.0f), 255.0f) * inv255;
            }

            const size_t row = (size_t)th * 16 + r;
            const size_t col = (size_t)tw * 128 + c4;
            const size_t o = outBase + row * W + col;
            __builtin_nontemporal_store(R,  (f32x4*)(out + o));
            __builtin_nontemporal_store(G,  (f32x4*)(out + o + planeStride));
            __builtin_nontemporal_store(Bv, (f32x4*)(out + o + 2 * planeStride));
        }
    }
}

extern "C" void kernel_launch(void* const* d_in, const int* in_sizes, int n_in,
                              void* d_out, int out_size, void* d_ws, size_t ws_size,
                              hipStream_t stream) {
    (void)in_sizes; (void)n_in; (void)d_ws; (void)ws_size; (void)out_size;
    const float* yg      = (const float*)d_in[0];
    const float* cbg     = (const float*)d_in[1];
    const float* crg     = (const float*)d_in[2];
    const float* y_table = (const float*)d_in[3];
    const float* c_table = (const float*)d_in[4];
    const float* alpha   = (const float*)d_in[5];
    const float* dct     = (const float*)d_in[6];
    const float* shiftp  = (const float*)d_in[7];
    const float* matp    = (const float*)d_in[8];
    const int*   factor  = (const int*)d_in[11];
    float* outp = (float*)d_out;

    dim3 grid(W / 128, H / 16, 8);   // (16, 128, 8)
    jpeg_decode_kernel<<<grid, 256, 0, stream>>>(
        yg, cbg, crg, y_table, c_table, alpha, dct, shiftp, matp, factor, outp);
}